// Round 12
// baseline (198.777 us; speedup 1.0000x reference)
//
#include <hip/hip_runtime.h>
#include <math.h>

#define S_LEN 2048
#define HID   1024
#define NH    16
#define HD    64
#define NM    128
#define CAUG  192
#define NCHW  16            // chunks (KC=32) per wave-group; block covers 32, grid.z covers 64

constexpr float ALPHA = 0.9f;

typedef __attribute__((ext_vector_type(8))) short bf16x8;
typedef __attribute__((ext_vector_type(4))) short bf16x4;
typedef __attribute__((ext_vector_type(4))) float f32x4;
typedef __attribute__((ext_vector_type(4))) int   int4v;

#define MFMA(a,b,c) __builtin_amdgcn_mfma_f32_16x16x32_bf16(a,b,c,0,0,0)

static __device__ inline short f2bf(float f) {
    unsigned u = __float_as_uint(f);
    u += 0x7fffu + ((u >> 16) & 1u);      // RNE
    return (short)(u >> 16);
}
static __device__ inline float bf2f(short s) {
    return __uint_as_float(((unsigned)(unsigned short)s) << 16);
}

// ---------------------------------------------------------------------------
// omega f32 [h][d][m] -> bf16 transposed om_t [h][m][d]
// ---------------------------------------------------------------------------
__global__ __launch_bounds__(256)
void omt_kernel(const float* __restrict__ omega, short* __restrict__ omtb)
{
    int i = blockIdx.x * 256 + threadIdx.x;   // 131072 = 16*64*128
    if (i >= 131072) return;
    int h = i >> 13, rem = i & 8191;
    int d = rem >> 7, m = rem & 127;
    omtb[((h * 128 + m) << 6) + d] = f2bf(omega[i]);
}

// ---------------------------------------------------------------------------
// bf16 MFMA GEMM with FUSED f32->bf16 conversion of A (optional) and W (always).
// C = A(2048x1024) @ W(1024x1024)^T + bias.  BM=64, BN=128, BK=32; 4 waves.
// mode 0: C bf16 [m][1024];  mode 1: C bf16 transposed [n][Mrows];  mode 2: C f32
// ---------------------------------------------------------------------------
__global__ __launch_bounds__(256)
void gemm_mfma(const void* __restrict__ Ax, int a_f32,
               const float* __restrict__ W0, const float* __restrict__ b0, void* C0,
               const float* __restrict__ W1, const float* __restrict__ b1, void* C1,
               const float* __restrict__ W2, const float* __restrict__ b2, void* C2,
               int m0_, int m1_, int m2_, int Mrows)
{
    const float* W; const float* bias; void* C; int mode;
    if (blockIdx.z == 0)      { W = W0; bias = b0; C = C0; mode = m0_; }
    else if (blockIdx.z == 1) { W = W1; bias = b1; C = C1; mode = m1_; }
    else                      { W = W2; bias = b2; C = C2; mode = m2_; }

    __shared__ short As[64][40];     // 32 k-elems + 4 pad -> 80B rows
    __shared__ short Bs[128][40];

    const int tid = threadIdx.x;
    const int wave = tid >> 6, lane = tid & 63;
    const int l15 = lane & 15, l4 = lane >> 4;
    const int wm = wave >> 1, wn = wave & 1;
    const int m0 = blockIdx.y * 64, n0 = blockIdx.x * 128;

    const int srow = tid >> 2;            // 0..63
    const int se   = (tid & 3) * 8;       // elem offset within 32-elem k-chunk

    f32x4 acc[2][4];
#pragma unroll
    for (int i = 0; i < 2; ++i)
#pragma unroll
        for (int j = 0; j < 4; ++j) acc[i][j] = (f32x4){0.f,0.f,0.f,0.f};

    auto cvt8 = [](float4 f0, float4 f1) -> int4v {
        bf16x8 c;
        c[0]=f2bf(f0.x); c[1]=f2bf(f0.y); c[2]=f2bf(f0.z); c[3]=f2bf(f0.w);
        c[4]=f2bf(f1.x); c[5]=f2bf(f1.y); c[6]=f2bf(f1.z); c[7]=f2bf(f1.w);
        return *(int4v*)&c;
    };
    auto ldA = [&](int ks) -> int4v {
        if (a_f32) {
            const float* p = (const float*)Ax + (size_t)(m0 + srow) * 1024 + ks * 32 + se;
            return cvt8(*(const float4*)p, *(const float4*)(p + 4));
        }
        return *(const int4v*)((const char*)Ax + (size_t)(m0 + srow) * 2048 + ks * 64 + se * 2);
    };
    auto ldW = [&](int ks, int rofs) -> int4v {
        const float* p = W + (size_t)(n0 + rofs + srow) * 1024 + ks * 32 + se;
        return cvt8(*(const float4*)p, *(const float4*)(p + 4));
    };

    int4v apre = ldA(0), bpre0 = ldW(0, 0), bpre1 = ldW(0, 64);

    for (int ks = 0; ks < 32; ++ks) {
        __syncthreads();
        *(int4v*)((char*)&As[0][0] + srow * 80 + se * 2) = apre;
        *(int4v*)((char*)&Bs[0][0] + srow * 80 + se * 2) = bpre0;
        *(int4v*)((char*)&Bs[0][0] + (64 + srow) * 80 + se * 2) = bpre1;
        __syncthreads();
        if (ks + 1 < 32) {
            apre  = ldA(ks + 1);
            bpre0 = ldW(ks + 1, 0);
            bpre1 = ldW(ks + 1, 64);
        }
        bf16x8 af[2], bf[4];
#pragma unroll
        for (int mi = 0; mi < 2; ++mi)
            af[mi] = *(const bf16x8*)((const char*)&As[0][0] + (wm*32 + mi*16 + l15) * 80 + l4*16);
#pragma unroll
        for (int nj = 0; nj < 4; ++nj)
            bf[nj] = *(const bf16x8*)((const char*)&Bs[0][0] + (wn*64 + nj*16 + l15) * 80 + l4*16);
#pragma unroll
        for (int mi = 0; mi < 2; ++mi)
#pragma unroll
            for (int nj = 0; nj < 4; ++nj)
                acc[mi][nj] = MFMA(af[mi], bf[nj], acc[mi][nj]);
    }

#pragma unroll
    for (int nj = 0; nj < 4; ++nj) {
        const int nglob = n0 + wn*64 + nj*16 + l15;
        const float bn = bias[nglob];
#pragma unroll
        for (int mi = 0; mi < 2; ++mi) {
            const int mbase = m0 + wm*32 + mi*16 + l4*4;
            if (mode == 0) {
#pragma unroll
                for (int r = 0; r < 4; ++r)
                    ((short*)C)[(size_t)(mbase + r) * 1024 + nglob] = f2bf(acc[mi][nj][r] + bn);
            } else if (mode == 1) {
                bf16x4 pk;
#pragma unroll
                for (int r = 0; r < 4; ++r) pk[r] = f2bf(acc[mi][nj][r] + bn);
                *(bf16x4*)((short*)C + (size_t)nglob * Mrows + mbase) = pk;
            } else {
#pragma unroll
                for (int r = 0; r < 4; ++r)
                    ((float*)C)[(size_t)(mbase + r) * 1024 + nglob] = acc[mi][nj][r] + bn;
            }
        }
    }
}

// ---------------------------------------------------------------------------
// phi2 (MFMA): per block = one (src, head, 64 s-rows)
// ---------------------------------------------------------------------------
__global__ __launch_bounds__(256)
void phi2_kernel(const short* __restrict__ qbuf, const short* __restrict__ kbuf,
                 const short* __restrict__ omtb, const float* __restrict__ rffb,
                 short* __restrict__ Qa, short* __restrict__ Ka)
{
    __shared__ short om[128][72];
    __shared__ float bsh[128];

    const int src = blockIdx.z, h = blockIdx.y;
    const int s0 = blockIdx.x * 64;
    const short* X = src ? kbuf : qbuf;
    short* Out     = src ? Ka : Qa;
    const float fq   = src ? 1.0f : (ALPHA * 0.125f);
    const float fphi = src ? 1.0f : ((1.0f - ALPHA) * 0.125f);

    const int tid = threadIdx.x, wave = tid >> 6, lane = tid & 63;
    const int l15 = lane & 15, l4 = lane >> 4;

    {
        const char* gsrc = (const char*)(omtb + ((size_t)h << 13));
#pragma unroll
        for (int it = 0; it < 4; ++it) {
            int f = tid * 16 + it * 4096;
            int row = f >> 7, colb = f & 127;
            *(int4v*)((char*)&om[0][0] + row * 144 + colb) = *(const int4v*)(gsrc + f);
        }
        if (tid < 128) bsh[tid] = rffb[h * 128 + tid];
    }
    __syncthreads();

    const int srow = s0 + wave * 16 + l15;

    bf16x8 xf[2];
#pragma unroll
    for (int cs = 0; cs < 2; ++cs)
        xf[cs] = *(const bf16x8*)(X + (size_t)srow * HID + h * HD + cs * 32 + l4 * 8);

    float ss = 0.f;
#pragma unroll
    for (int cs = 0; cs < 2; ++cs)
#pragma unroll
        for (int j = 0; j < 8; ++j) { float v = bf2f(xf[cs][j]); ss = fmaf(v, v, ss); }
    ss += __shfl_xor(ss, 16);
    ss += __shfl_xor(ss, 32);
    const float inv = 1.0f / (sqrtf(ss) + 1e-6f);

    bf16x8 qn[2];
#pragma unroll
    for (int cs = 0; cs < 2; ++cs) {
        bf16x8 o, w;
#pragma unroll
        for (int j = 0; j < 8; ++j) {
            float v = bf2f(xf[cs][j]);
            o[j] = f2bf(v * inv);
            w[j] = f2bf(v * fq);
        }
        qn[cs] = o;
        *(bf16x8*)(Out + ((size_t)h * S_LEN + srow) * CAUG + cs * 32 + l4 * 8) = w;
    }

    f32x4 pacc[8];
#pragma unroll
    for (int t = 0; t < 8; ++t) pacc[t] = (f32x4){0.f,0.f,0.f,0.f};
#pragma unroll
    for (int t = 0; t < 8; ++t)
#pragma unroll
        for (int cs = 0; cs < 2; ++cs) {
            bf16x8 bf = *(const bf16x8*)((const char*)&om[0][0] + (t*16 + l15) * 144 + cs*64 + l4*16);
            pacc[t] = MFMA(qn[cs], bf, pacc[t]);
        }

    float ph[8][4];
    float ps[4] = {0.f, 0.f, 0.f, 0.f};
#pragma unroll
    for (int t = 0; t < 8; ++t) {
        const float bv = bsh[t * 16 + l15];
#pragma unroll
        for (int r = 0; r < 4; ++r) {
            float p = pacc[t][r] + bv;
            float c = 0.125f * __cosf(p);
            ph[t][r] = c;
            ps[r] = fmaf(c, c, ps[r]);
        }
    }
#pragma unroll
    for (int r = 0; r < 4; ++r) {
        ps[r] += __shfl_xor(ps[r], 1);
        ps[r] += __shfl_xor(ps[r], 2);
        ps[r] += __shfl_xor(ps[r], 4);
        ps[r] += __shfl_xor(ps[r], 8);
    }
    float inv2[4];
#pragma unroll
    for (int r = 0; r < 4; ++r) inv2[r] = fphi / (sqrtf(ps[r]) + 1e-6f);

#pragma unroll
    for (int t = 0; t < 8; ++t)
#pragma unroll
        for (int r = 0; r < 4; ++r)
            Out[((size_t)h * S_LEN + s0 + wave * 16 + l4 * 4 + r) * CAUG + 64 + t * 16 + l15]
                = f2bf(ph[t][r] * inv2[r]);
}

// ---------------------------------------------------------------------------
// MFMA flash attention, BLOCK-LEVEL 2-WAY K-SPLIT for 4 blocks/CU residency.
// Grid (32 qtiles, 16 heads, 2 ksplits) = 1024 blocks = exactly 4/CU.
// Block: 64 q rows, 4 waves, 2 groups x 2 waves; group g covers 16 chunks
// (base = ksp*32 + g*16); each wave owns 32 q (qj=2).  K staged in per-group
// LDS (2 barriers/chunk); V fragments loaded direct global->reg at PV (TLP
// hides latency at 16 waves/CU).  Static-max softmax (p = exp(s+mask)) ->
// partials are plain sums: block writes bf16 O-partial + f32 l-partial, a
// tiny merge kernel combines the 2 splits.  LDS 35840 B, VGPR capped 128.
// ---------------------------------------------------------------------------
__global__ __launch_bounds__(256, 4)
void flash_mfma(const short* __restrict__ Qa, const short* __restrict__ Ka,
                const short* __restrict__ vt, const float* __restrict__ mask,
                short* __restrict__ Opart, float* __restrict__ Lpart)
{
    // [0,25600):      Ks[2 groups][32 rows][400B]
    // [25600,35840):  Pl[4 waves][32 rows][80B]
    // combine: scrO f32[64][68] @ 0 (17408B); scrL f32[64] @ 25600
    __shared__ char smem[35840];

    const int tid = threadIdx.x;
    const int wave = tid >> 6, lane = tid & 63;
    const int l15 = lane & 15, l4 = lane >> 4;
    const int g = wave >> 1, sub = wave & 1;
    const int h = blockIdx.y;
    const int ksp = blockIdx.z;
    const int q0 = blockIdx.x * 64 + sub * 32;

    char* Kbuf = smem + g * 12800;
    char* PlW  = smem + 25600 + wave * 2560;

    // Q' fragments: 32 q rows per wave
    bf16x8 qf[2][6];
#pragma unroll
    for (int qj = 0; qj < 2; ++qj)
#pragma unroll
        for (int cs = 0; cs < 6; ++cs)
            qf[qj][cs] = *(const bf16x8*)(Qa + ((size_t)h * 2048 + q0 + qj*16 + l15) * CAUG + cs*32 + l4*8);

    f32x4 oacc[4][2];
#pragma unroll
    for (int di = 0; di < 4; ++di)
#pragma unroll
        for (int qj = 0; qj < 2; ++qj) oacc[di][qj] = (f32x4){0.f,0.f,0.f,0.f};
    float lsum[2] = {0.f, 0.f};

    // staging: 128 threads of the group stage 12288 B (6 x 16B each)
    const int t = tid & 127;
    int kr[6], kcb[6];
#pragma unroll
    for (int it = 0; it < 6; ++it) { int f = t*16 + it*2048; kr[it] = f/384; kcb[it] = f%384; }

    const char* Kg = (const char*)(Ka + (size_t)h * 2048 * CAUG);   // rows 384B
    const char* Vg = (const char*)(vt + (size_t)h * 64 * 2048);     // rows 4096B
    const int base = ksp * 32 + g * NCHW;

    int4v kpre[6];
    auto loadKpre = [&](int kt) {
        const char* kb = Kg + (size_t)kt * 12288;
#pragma unroll
        for (int it = 0; it < 6; ++it)
            kpre[it] = *(const int4v*)(kb + (size_t)kr[it]*384 + kcb[it]);
    };

    loadKpre(base);

    for (int i = 0; i < NCHW; ++i) {
        const int kt = base + i;
        __syncthreads();                       // group done reading previous chunk
#pragma unroll
        for (int it = 0; it < 6; ++it)
            *(int4v*)(Kbuf + kr[it]*400 + kcb[it]) = kpre[it];
        __syncthreads();                       // chunk staged
        if (i + 1 < NCHW) loadKpre(kt + 1);    // prefetch next K (regs)

        // ---- scores S^T (32 kpos x 32 q) ----
        f32x4 sacc[2][2];
#pragma unroll
        for (int fi = 0; fi < 2; ++fi)
#pragma unroll
            for (int qj = 0; qj < 2; ++qj) sacc[fi][qj] = (f32x4){0.f,0.f,0.f,0.f};
#pragma unroll
        for (int cs = 0; cs < 6; ++cs) {
            bf16x8 ka[2];
#pragma unroll
            for (int fi = 0; fi < 2; ++fi)
                ka[fi] = *(const bf16x8*)(Kbuf + (fi*16 + l15)*400 + cs*64 + l4*16);
#pragma unroll
            for (int fi = 0; fi < 2; ++fi)
#pragma unroll
                for (int qj = 0; qj < 2; ++qj)
                    sacc[fi][qj] = MFMA(ka[fi], qf[qj][cs], sacc[fi][qj]);
        }
        // ---- static-max softmax: p = exp(s + mask); accumulate l ----
#pragma unroll
        for (int fi = 0; fi < 2; ++fi) {
            float4 mk = *(const float4*)&mask[kt*32 + fi*16 + l4*4];
            float mv[4] = {mk.x * -10000.f, mk.y * -10000.f, mk.z * -10000.f, mk.w * -10000.f};
#pragma unroll
            for (int qj = 0; qj < 2; ++qj) {
                bf16x4 pk;
#pragma unroll
                for (int r = 0; r < 4; ++r) {
                    float p = __expf(sacc[fi][qj][r] + mv[r]);
                    lsum[qj] += p;
                    pk[r] = f2bf(p);
                }
                *(bf16x4*)(PlW + (qj*16 + l15)*80 + fi*32 + l4*8) = pk;
            }
        }
        // ---- PV: O^T += V^T . P^T  (V direct from global; TLP hides it) ----
        {
            bf16x8 pb[2];
#pragma unroll
            for (int qj = 0; qj < 2; ++qj)
                pb[qj] = *(const bf16x8*)(PlW + (qj*16 + l15)*80 + l4*16);
#pragma unroll
            for (int di = 0; di < 4; ++di) {
                bf16x8 va = *(const bf16x8*)(Vg + (size_t)(di*16 + l15)*4096 + kt*64 + l4*16);
#pragma unroll
                for (int qj = 0; qj < 2; ++qj)
                    oacc[di][qj] = MFMA(va, pb[qj], oacc[di][qj]);
            }
        }
    }

    // reduce l across the 4 kpos lane-groups
#pragma unroll
    for (int qj = 0; qj < 2; ++qj) {
        lsum[qj] += __shfl_xor(lsum[qj], 16);
        lsum[qj] += __shfl_xor(lsum[qj], 32);
    }

    // ---- combine the two groups in LDS, then coalesced partial export ----
    __syncthreads();
    float* scrO = (float*)smem;               // [64][68] f32
    float* scrL = (float*)(smem + 25600);     // [64] f32
    if (g == 1) {
#pragma unroll
        for (int qj = 0; qj < 2; ++qj) {
            const int row = sub*32 + qj*16 + l15;
#pragma unroll
            for (int di = 0; di < 4; ++di)
                *(f32x4*)&scrO[(size_t)row*68 + di*16 + l4*4] = oacc[di][qj];
            if (l4 == 0) scrL[row] = lsum[qj];
        }
    }
    __syncthreads();
    if (g == 0) {
#pragma unroll
        for (int qj = 0; qj < 2; ++qj) {
            const int row = sub*32 + qj*16 + l15;
            const float l = lsum[qj] + scrL[row];
#pragma unroll
            for (int di = 0; di < 4; ++di) {
                f32x4 o2 = *(const f32x4*)&scrO[(size_t)row*68 + di*16 + l4*4];
                *(f32x4*)&scrO[(size_t)row*68 + di*16 + l4*4] = oacc[di][qj] + o2;
            }
            if (l4 == 0) scrL[row] = l;
        }
    }
    __syncthreads();
    if (tid < 128) {
        const size_t obase = ((size_t)(ksp * NH + h) * 2048 + blockIdx.x * 64);
#pragma unroll
        for (int it2 = 0; it2 < 8; ++it2) {
            int idx = it2 * 128 + tid;        // 0..1023 -> (q, 4-elem d chunk)
            int q = idx >> 4, dc = (idx & 15) * 4;
            f32x4 v = *(const f32x4*)&scrO[(size_t)q*68 + dc];
            bf16x4 ob;
#pragma unroll
            for (int r = 0; r < 4; ++r) ob[r] = f2bf(v[r]);
            *(bf16x4*)(Opart + (obase + q) * 64 + dc) = ob;
        }
        if (tid < 64) Lpart[obase + tid] = scrL[tid];
    }
}

// ---------------------------------------------------------------------------
// merge the 2 flash K-split partials -> ctx bf16 [s][1024]
// ---------------------------------------------------------------------------
__global__ __launch_bounds__(256)
void merge_kernel(const short* __restrict__ Opart, const float* __restrict__ Lpart,
                  short* __restrict__ ctxb)
{
    int tt = blockIdx.x * 256 + threadIdx.x;      // 524288 threads x 4 elems
    int e = tt * 4;
    int d = e & 63;
    int q = (e >> 6) & 2047;
    int h = e >> 17;
    size_t i0 = (size_t)h * 2048 + q;
    size_t i1 = (size_t)(NH + h) * 2048 + q;
    bf16x4 a = *(const bf16x4*)(Opart + i0 * 64 + d);
    bf16x4 b = *(const bf16x4*)(Opart + i1 * 64 + d);
    float inv = 1.0f / (Lpart[i0] + Lpart[i1]);
    bf16x4 o;
#pragma unroll
    for (int r = 0; r < 4; ++r) o[r] = f2bf((bf2f(a[r]) + bf2f(b[r])) * inv);
    *(bf16x4*)(ctxb + (size_t)q * 1024 + h * 64 + d) = o;
}

// ---------------------------------------------------------------------------
extern "C" void kernel_launch(void* const* d_in, const int* in_sizes, int n_in,
                              void* d_out, int out_size, void* d_ws, size_t ws_size,
                              hipStream_t stream)
{
    const float* hs    = (const float*)d_in[0];
    const float* mask  = (const float*)d_in[1];
    const float* Wq    = (const float*)d_in[2];
    const float* bq    = (const float*)d_in[3];
    const float* Wk    = (const float*)d_in[4];
    const float* bk    = (const float*)d_in[5];
    const float* Wv    = (const float*)d_in[6];
    const float* bv    = (const float*)d_in[7];
    const float* Wo    = (const float*)d_in[8];
    const float* bo    = (const float*)d_in[9];
    const float* omega = (const float*)d_in[10];
    const float* rffb  = (const float*)d_in[11];
    float* out = (float*)d_out;

    short* wsS  = (short*)d_ws;
    short* qb   = wsS;                       // 2,097,152
    short* kb   = qb   + 2097152;
    short* vtb  = kb   + 2097152;            // [h][d][s]
    short* ctxb = vtb  + 2097152;
    short* QaB  = ctxb + 2097152;            // 6,291,456  [h][s][192]
    short* KaB  = QaB  + 6291456;
    short* omtb = KaB  + 6291456;            // 131,072    [h][m][d]
    short* OpS  = omtb + 131072;             // 4,194,304  bf16 [2][16][2048][64]
    float* LpF  = (float*)(OpS + 4194304);   // 65,536 f32 [2][16][2048]

    omt_kernel<<<512, 256, 0, stream>>>(omega, omtb);
    gemm_mfma<<<dim3(8, 32, 3), 256, 0, stream>>>(hs, 1, Wq, bq, qb, Wk, bk, kb, Wv, bv, vtb,
                                                  0, 0, 1, S_LEN);
    phi2_kernel<<<dim3(32, 16, 2), 256, 0, stream>>>(qb, kb, omtb, rffb, QaB, KaB);
    flash_mfma<<<dim3(32, 16, 2), 256, 0, stream>>>(QaB, KaB, vtb, mask, OpS, LpF);
    merge_kernel<<<2048, 256, 0, stream>>>(OpS, LpF, ctxb);
    gemm_mfma<<<dim3(8, 32, 1), 256, 0, stream>>>(ctxb, 0, Wo, bo, out, Wo, bo, out, Wo, bo, out,
                                                  2, 2, 2, S_LEN);
}

// Round 13
// 135.797 us; speedup vs baseline: 1.4638x; 1.4638x over previous
//
#include <hip/hip_runtime.h>
#include <math.h>

#define S_LEN 2048
#define HID   1024
#define NH    16
#define HD    64
#define NM    128
#define CAUG  192
#define KSPL  4             // K-splits (blocks); each block covers 16 chunks of 32 kpos

constexpr float ALPHA = 0.9f;

typedef __attribute__((ext_vector_type(8))) short bf16x8;
typedef __attribute__((ext_vector_type(4))) short bf16x4;
typedef __attribute__((ext_vector_type(4))) float f32x4;
typedef __attribute__((ext_vector_type(4))) int   int4v;

#define MFMA(a,b,c) __builtin_amdgcn_mfma_f32_16x16x32_bf16(a,b,c,0,0,0)

static __device__ inline short f2bf(float f) {
    unsigned u = __float_as_uint(f);
    u += 0x7fffu + ((u >> 16) & 1u);      // RNE
    return (short)(u >> 16);
}
static __device__ inline float bf2f(short s) {
    return __uint_as_float(((unsigned)(unsigned short)s) << 16);
}

// ---------------------------------------------------------------------------
// fp32 -> bf16 conversion: hs + 4 weights, float4-wide; tail range does the
// omega [h][d][m] -> om_t bf16 [h][m][d] transpose.
// ---------------------------------------------------------------------------
__global__ __launch_bounds__(256)
void conv_kernel(const float* __restrict__ hs,
                 const float* __restrict__ Wq, const float* __restrict__ Wk,
                 const float* __restrict__ Wv, const float* __restrict__ Wo,
                 const float* __restrict__ omega,
                 short* __restrict__ hsb, short* __restrict__ wqb, short* __restrict__ wkb,
                 short* __restrict__ wvb, short* __restrict__ wob, short* __restrict__ omtb)
{
    int i = blockIdx.x * 256 + threadIdx.x;           // f4-unit index
    if (i >= 1605632) return;
    if (i >= 1572864) {                               // omega transpose tail
        int j = (i - 1572864) * 4;                    // elem index in [h][d][m]
        int h = j >> 13, rem = j & 8191;
        int d = rem >> 7, m = rem & 127;
        float4 v = *(const float4*)(omega + j);       // 4 consecutive m
        short* dst = omtb + ((h * 128 + m) << 6) + d; // [h][m][d]
        dst[0]       = f2bf(v.x);
        dst[64]      = f2bf(v.y);
        dst[128]     = f2bf(v.z);
        dst[192]     = f2bf(v.w);
        return;
    }
    const float* src; short* dst; int off;
    if (i < 524288) { src = hs; dst = hsb; off = i; }
    else {
        int j = i - 524288;
        int r = j >> 18;              // 0..3
        off = j & 262143;
        src = (r == 0) ? Wq : (r == 1) ? Wk : (r == 2) ? Wv : Wo;
        dst = (r == 0) ? wqb : (r == 1) ? wkb : (r == 2) ? wvb : wob;
    }
    float4 v = ((const float4*)src)[off];
    bf16x4 o; o[0] = f2bf(v.x); o[1] = f2bf(v.y); o[2] = f2bf(v.z); o[3] = f2bf(v.w);
    ((bf16x4*)dst)[off] = o;
}

// ---------------------------------------------------------------------------
// bf16 MFMA GEMM: C = A(2048x1024) @ W(1024x1024)^T + bias
// BM=64, BN=128, BK=32; 4 waves 2(m)x2(n), wave tile 32x64, acc[2][4].
// mode 0: C bf16 [m][1024];  mode 1: C bf16 transposed [n][Mrows];  mode 2: C f32
// ---------------------------------------------------------------------------
__global__ __launch_bounds__(256)
void gemm_mfma(const short* __restrict__ A,
               const short* __restrict__ W0, const float* __restrict__ b0, void* C0,
               const short* __restrict__ W1, const float* __restrict__ b1, void* C1,
               const short* __restrict__ W2, const float* __restrict__ b2, void* C2,
               int m0_, int m1_, int m2_, int Mrows)
{
    const short* W; const float* bias; void* C; int mode;
    if (blockIdx.z == 0)      { W = W0; bias = b0; C = C0; mode = m0_; }
    else if (blockIdx.z == 1) { W = W1; bias = b1; C = C1; mode = m1_; }
    else                      { W = W2; bias = b2; C = C2; mode = m2_; }

    __shared__ short As[64][40];
    __shared__ short Bs[128][40];

    const int tid = threadIdx.x;
    const int wave = tid >> 6, lane = tid & 63;
    const int l15 = lane & 15, l4 = lane >> 4;
    const int wm = wave >> 1, wn = wave & 1;
    const int m0 = blockIdx.y * 64, n0 = blockIdx.x * 128;

    const int srow = tid >> 2;
    const int scol = (tid & 3) * 16;

    f32x4 acc[2][4];
#pragma unroll
    for (int i = 0; i < 2; ++i)
#pragma unroll
        for (int j = 0; j < 4; ++j) acc[i][j] = (f32x4){0.f,0.f,0.f,0.f};

    int4v apre, bpre0, bpre1;
    apre  = *(const int4v*)((const char*)A + (size_t)(m0 + srow) * 2048 + scol);
    bpre0 = *(const int4v*)((const char*)W + (size_t)(n0 + srow) * 2048 + scol);
    bpre1 = *(const int4v*)((const char*)W + (size_t)(n0 + 64 + srow) * 2048 + scol);

    for (int ks = 0; ks < 32; ++ks) {
        __syncthreads();
        *(int4v*)((char*)&As[0][0] + srow * 80 + scol) = apre;
        *(int4v*)((char*)&Bs[0][0] + srow * 80 + scol) = bpre0;
        *(int4v*)((char*)&Bs[0][0] + (64 + srow) * 80 + scol) = bpre1;
        __syncthreads();
        if (ks + 1 < 32) {
            const int kb = (ks + 1) * 64;
            apre  = *(const int4v*)((const char*)A + (size_t)(m0 + srow) * 2048 + kb + scol);
            bpre0 = *(const int4v*)((const char*)W + (size_t)(n0 + srow) * 2048 + kb + scol);
            bpre1 = *(const int4v*)((const char*)W + (size_t)(n0 + 64 + srow) * 2048 + kb + scol);
        }
        bf16x8 af[2], bf[4];
#pragma unroll
        for (int mi = 0; mi < 2; ++mi)
            af[mi] = *(const bf16x8*)((const char*)&As[0][0] + (wm*32 + mi*16 + l15) * 80 + l4*16);
#pragma unroll
        for (int nj = 0; nj < 4; ++nj)
            bf[nj] = *(const bf16x8*)((const char*)&Bs[0][0] + (wn*64 + nj*16 + l15) * 80 + l4*16);
#pragma unroll
        for (int mi = 0; mi < 2; ++mi)
#pragma unroll
            for (int nj = 0; nj < 4; ++nj)
                acc[mi][nj] = MFMA(af[mi], bf[nj], acc[mi][nj]);
    }

#pragma unroll
    for (int nj = 0; nj < 4; ++nj) {
        const int nglob = n0 + wn*64 + nj*16 + l15;
        const float bn = bias[nglob];
#pragma unroll
        for (int mi = 0; mi < 2; ++mi) {
            const int mbase = m0 + wm*32 + mi*16 + l4*4;
            if (mode == 0) {
#pragma unroll
                for (int r = 0; r < 4; ++r)
                    ((short*)C)[(size_t)(mbase + r) * 1024 + nglob] = f2bf(acc[mi][nj][r] + bn);
            } else if (mode == 1) {
                bf16x4 pk;
#pragma unroll
                for (int r = 0; r < 4; ++r) pk[r] = f2bf(acc[mi][nj][r] + bn);
                *(bf16x4*)((short*)C + (size_t)nglob * Mrows + mbase) = pk;
            } else {
#pragma unroll
                for (int r = 0; r < 4; ++r)
                    ((float*)C)[(size_t)(mbase + r) * 1024 + nglob] = acc[mi][nj][r] + bn;
            }
        }
    }
}

// ---------------------------------------------------------------------------
// phi2 (MFMA): per block = one (src, head, 64 s-rows)
// ---------------------------------------------------------------------------
__global__ __launch_bounds__(256)
void phi2_kernel(const short* __restrict__ qbuf, const short* __restrict__ kbuf,
                 const short* __restrict__ omtb, const float* __restrict__ rffb,
                 short* __restrict__ Qa, short* __restrict__ Ka)
{
    __shared__ short om[128][72];
    __shared__ float bsh[128];

    const int src = blockIdx.z, h = blockIdx.y;
    const int s0 = blockIdx.x * 64;
    const short* X = src ? kbuf : qbuf;
    short* Out     = src ? Ka : Qa;
    const float fq   = src ? 1.0f : (ALPHA * 0.125f);
    const float fphi = src ? 1.0f : ((1.0f - ALPHA) * 0.125f);

    const int tid = threadIdx.x, wave = tid >> 6, lane = tid & 63;
    const int l15 = lane & 15, l4 = lane >> 4;

    {
        const char* gsrc = (const char*)(omtb + ((size_t)h << 13));
#pragma unroll
        for (int it = 0; it < 4; ++it) {
            int f = tid * 16 + it * 4096;
            int row = f >> 7, colb = f & 127;
            *(int4v*)((char*)&om[0][0] + row * 144 + colb) = *(const int4v*)(gsrc + f);
        }
        if (tid < 128) bsh[tid] = rffb[h * 128 + tid];
    }
    __syncthreads();

    const int srow = s0 + wave * 16 + l15;

    bf16x8 xf[2];
#pragma unroll
    for (int cs = 0; cs < 2; ++cs)
        xf[cs] = *(const bf16x8*)(X + (size_t)srow * HID + h * HD + cs * 32 + l4 * 8);

    float ss = 0.f;
#pragma unroll
    for (int cs = 0; cs < 2; ++cs)
#pragma unroll
        for (int j = 0; j < 8; ++j) { float v = bf2f(xf[cs][j]); ss = fmaf(v, v, ss); }
    ss += __shfl_xor(ss, 16);
    ss += __shfl_xor(ss, 32);
    const float inv = 1.0f / (sqrtf(ss) + 1e-6f);

    bf16x8 qn[2];
#pragma unroll
    for (int cs = 0; cs < 2; ++cs) {
        bf16x8 o, w;
#pragma unroll
        for (int j = 0; j < 8; ++j) {
            float v = bf2f(xf[cs][j]);
            o[j] = f2bf(v * inv);
            w[j] = f2bf(v * fq);
        }
        qn[cs] = o;
        *(bf16x8*)(Out + ((size_t)h * S_LEN + srow) * CAUG + cs * 32 + l4 * 8) = w;
    }

    f32x4 pacc[8];
#pragma unroll
    for (int t = 0; t < 8; ++t) pacc[t] = (f32x4){0.f,0.f,0.f,0.f};
#pragma unroll
    for (int t = 0; t < 8; ++t)
#pragma unroll
        for (int cs = 0; cs < 2; ++cs) {
            bf16x8 bf = *(const bf16x8*)((const char*)&om[0][0] + (t*16 + l15) * 144 + cs*64 + l4*16);
            pacc[t] = MFMA(qn[cs], bf, pacc[t]);
        }

    float ph[8][4];
    float ps[4] = {0.f, 0.f, 0.f, 0.f};
#pragma unroll
    for (int t = 0; t < 8; ++t) {
        const float bv = bsh[t * 16 + l15];
#pragma unroll
        for (int r = 0; r < 4; ++r) {
            float p = pacc[t][r] + bv;
            float c = 0.125f * __cosf(p);
            ph[t][r] = c;
            ps[r] = fmaf(c, c, ps[r]);
        }
    }
#pragma unroll
    for (int r = 0; r < 4; ++r) {
        ps[r] += __shfl_xor(ps[r], 1);
        ps[r] += __shfl_xor(ps[r], 2);
        ps[r] += __shfl_xor(ps[r], 4);
        ps[r] += __shfl_xor(ps[r], 8);
    }
    float inv2[4];
#pragma unroll
    for (int r = 0; r < 4; ++r) inv2[r] = fphi / (sqrtf(ps[r]) + 1e-6f);

#pragma unroll
    for (int t = 0; t < 8; ++t)
#pragma unroll
        for (int r = 0; r < 4; ++r)
            Out[((size_t)h * S_LEN + s0 + wave * 16 + l4 * 4 + r) * CAUG + 64 + t * 16 + l15]
                = f2bf(ph[t][r] * inv2[r]);
}

// ---------------------------------------------------------------------------
// MFMA flash attention, HIGH-OCCUPANCY 128-thread blocks.
// Block = 2 waves sharing one K chunk (LDS, swizzled) + one V^T chunk (LDS,
// swizzled); each wave owns 32 q rows (qj=2) -> q-tile 64, NO combine needed.
// 4-way K-split across blocks: grid (32,16,4) = 2048 blocks = 8 blocks/CU
// = 16 waves/CU = 4 waves/SIMD (LDS exactly 20480 B, VGPR capped 128).
// Static-max softmax (scores bounded) -> partials are plain sums; block
// writes bf16 O-partial + f32 l-partial; merge kernel combines 4 splits.
// ---------------------------------------------------------------------------
__global__ __launch_bounds__(128, 4)
void flash_mfma(const short* __restrict__ Qa, const short* __restrict__ Ka,
                const short* __restrict__ vt, const float* __restrict__ mask,
                short* __restrict__ Opart, float* __restrict__ Lpart)
{
    // [0,12288):     Kbuf 32 rows x 384B, byte ^= ((row&7)<<4)
    // [12288,16384): Vbuf 64 rows x 64B,  byte ^= ((row&3)<<4)
    // [16384,20480): P[wave] 32 rows x 64B, byte ^= ((row&3)<<4)
    __shared__ char smem[20480];

    const int tid = threadIdx.x;
    const int wave = tid >> 6, lane = tid & 63;
    const int l15 = lane & 15, l4 = lane >> 4;
    const int h = blockIdx.y, ksp = blockIdx.z;
    const int q0 = blockIdx.x * 64 + wave * 32;

    char* Kbuf = smem;
    char* Vbuf = smem + 12288;
    char* Pb   = smem + 16384 + wave * 2048;

    // Q' fragments: 32 q rows per wave
    bf16x8 qf[2][6];
#pragma unroll
    for (int qj = 0; qj < 2; ++qj)
#pragma unroll
        for (int cs = 0; cs < 6; ++cs)
            qf[qj][cs] = *(const bf16x8*)(Qa + ((size_t)h * 2048 + q0 + qj*16 + l15) * CAUG + cs*32 + l4*8);

    f32x4 oacc[4][2];
#pragma unroll
    for (int di = 0; di < 4; ++di)
#pragma unroll
        for (int qj = 0; qj < 2; ++qj) oacc[di][qj] = (f32x4){0.f,0.f,0.f,0.f};
    float lsum[2] = {0.f, 0.f};

    // staging geometry: 128 threads; K 12288B (6x16B/thr), V 4096B (2x16B/thr)
    int gK[6], wrK[6];
#pragma unroll
    for (int it = 0; it < 6; ++it) {
        int f = tid * 16 + it * 2048;
        int row = f / 384, col = f - row * 384;
        gK[it] = f;
        wrK[it] = row * 384 + (col ^ ((row & 7) << 4));
    }
    int gVrow[2], gVcol[2], wrV[2];
#pragma unroll
    for (int it = 0; it < 2; ++it) {
        int f = tid * 16 + it * 2048;
        int row = f >> 6, col = f & 63;
        gVrow[it] = row; gVcol[it] = col;
        wrV[it] = row * 64 + (col ^ ((row & 3) << 4));
    }

    const char* Kg = (const char*)(Ka + (size_t)h * 2048 * CAUG);   // rows 384B
    const char* Vg = (const char*)(vt + (size_t)h * 64 * 2048);     // rows 4096B
    const int base = ksp * 16;
    const int swP = (l15 & 3) << 4;     // P row swizzle (row = qj*16+l15)
    const int swK = (l15 & 7) << 4;     // K row swizzle (row = fi*16+l15)

    for (int i = 0; i < 16; ++i) {
        const int kt = base + i;
        // issue global loads for this chunk (latency overlaps barrier wait + TLP)
        int4v kv[6], vv[2];
        const char* kb = Kg + (size_t)kt * 12288;
#pragma unroll
        for (int it = 0; it < 6; ++it)
            kv[it] = *(const int4v*)(kb + gK[it]);
#pragma unroll
        for (int it = 0; it < 2; ++it)
            vv[it] = *(const int4v*)(Vg + (size_t)gVrow[it] * 4096 + kt * 64 + gVcol[it]);
        __syncthreads();                       // readers of previous chunk done
#pragma unroll
        for (int it = 0; it < 6; ++it) *(int4v*)(Kbuf + wrK[it]) = kv[it];
#pragma unroll
        for (int it = 0; it < 2; ++it) *(int4v*)(Vbuf + wrV[it]) = vv[it];
        __syncthreads();                       // chunk staged

        // ---- scores S^T (32 kpos x 32 q) ----
        f32x4 sacc[2][2];
#pragma unroll
        for (int fi = 0; fi < 2; ++fi)
#pragma unroll
            for (int qj = 0; qj < 2; ++qj) sacc[fi][qj] = (f32x4){0.f,0.f,0.f,0.f};
#pragma unroll
        for (int cs = 0; cs < 6; ++cs) {
            bf16x8 ka[2];
#pragma unroll
            for (int fi = 0; fi < 2; ++fi)
                ka[fi] = *(const bf16x8*)(Kbuf + (fi*16 + l15)*384 + ((cs*64 + l4*16) ^ swK));
#pragma unroll
            for (int fi = 0; fi < 2; ++fi)
#pragma unroll
                for (int qj = 0; qj < 2; ++qj)
                    sacc[fi][qj] = MFMA(ka[fi], qf[qj][cs], sacc[fi][qj]);
        }
        // ---- static-max softmax: p = exp(s + mask); accumulate l ----
#pragma unroll
        for (int fi = 0; fi < 2; ++fi) {
            float4 mk = *(const float4*)&mask[kt*32 + fi*16 + l4*4];
            float mv[4] = {mk.x * -10000.f, mk.y * -10000.f, mk.z * -10000.f, mk.w * -10000.f};
#pragma unroll
            for (int qj = 0; qj < 2; ++qj) {
                bf16x4 pk;
#pragma unroll
                for (int r = 0; r < 4; ++r) {
                    float p = __expf(sacc[fi][qj][r] + mv[r]);
                    lsum[qj] += p;
                    pk[r] = f2bf(p);
                }
                *(bf16x4*)(Pb + (qj*16 + l15)*64 + ((fi*32 + l4*8) ^ swP)) = pk;
            }
        }
        // ---- PV: O^T += V^T . P^T ----
        {
            bf16x8 pb[2];
#pragma unroll
            for (int qj = 0; qj < 2; ++qj)
                pb[qj] = *(const bf16x8*)(Pb + (qj*16 + l15)*64 + ((l4*16) ^ swP));
#pragma unroll
            for (int di = 0; di < 4; ++di) {
                const int vrow = di*16 + l15;
                bf16x8 va = *(const bf16x8*)(Vbuf + vrow*64 + ((l4*16) ^ ((vrow & 3) << 4)));
#pragma unroll
                for (int qj = 0; qj < 2; ++qj)
                    oacc[di][qj] = MFMA(va, pb[qj], oacc[di][qj]);
            }
        }
    }

    // reduce l across the 4 kpos lane-groups
#pragma unroll
    for (int qj = 0; qj < 2; ++qj) {
        lsum[qj] += __shfl_xor(lsum[qj], 16);
        lsum[qj] += __shfl_xor(lsum[qj], 32);
    }

    // ---- export bf16 O-partial + f32 l-partial (no cross-wave combine) ----
    const size_t obase = (size_t)(ksp * NH + h) * 2048 + q0;
#pragma unroll
    for (int qj = 0; qj < 2; ++qj) {
        const size_t orow = obase + qj*16 + l15;
#pragma unroll
        for (int di = 0; di < 4; ++di) {
            bf16x4 ob;
#pragma unroll
            for (int r = 0; r < 4; ++r) ob[r] = f2bf(oacc[di][qj][r]);
            *(bf16x4*)(Opart + orow * 64 + di*16 + l4*4) = ob;
        }
        if (l4 == 0) Lpart[orow] = lsum[qj];
    }
}

// ---------------------------------------------------------------------------
// merge the 4 flash K-split partials -> ctx bf16 [s][1024]
// ---------------------------------------------------------------------------
__global__ __launch_bounds__(256)
void merge_kernel(const short* __restrict__ Opart, const float* __restrict__ Lpart,
                  short* __restrict__ ctxb)
{
    int tt = blockIdx.x * 256 + threadIdx.x;      // 524288 threads x 4 elems
    int e = tt * 4;
    int d = e & 63;
    int q = (e >> 6) & 2047;
    int h = e >> 17;
    float acc[4] = {0.f, 0.f, 0.f, 0.f};
    float L = 0.f;
#pragma unroll
    for (int s = 0; s < KSPL; ++s) {
        size_t idx = (size_t)(s * NH + h) * 2048 + q;
        bf16x4 a = *(const bf16x4*)(Opart + idx * 64 + d);
        L += Lpart[idx];
#pragma unroll
        for (int r = 0; r < 4; ++r) acc[r] += bf2f(a[r]);
    }
    float inv = 1.0f / L;
    bf16x4 o;
#pragma unroll
    for (int r = 0; r < 4; ++r) o[r] = f2bf(acc[r] * inv);
    *(bf16x4*)(ctxb + (size_t)q * 1024 + h * 64 + d) = o;
}

// ---------------------------------------------------------------------------
extern "C" void kernel_launch(void* const* d_in, const int* in_sizes, int n_in,
                              void* d_out, int out_size, void* d_ws, size_t ws_size,
                              hipStream_t stream)
{
    const float* hs    = (const float*)d_in[0];
    const float* mask  = (const float*)d_in[1];
    const float* Wq    = (const float*)d_in[2];
    const float* bq    = (const float*)d_in[3];
    const float* Wk    = (const float*)d_in[4];
    const float* bk    = (const float*)d_in[5];
    const float* Wv    = (const float*)d_in[6];
    const float* bv    = (const float*)d_in[7];
    const float* Wo    = (const float*)d_in[8];
    const float* bo    = (const float*)d_in[9];
    const float* omega = (const float*)d_in[10];
    const float* rffb  = (const float*)d_in[11];
    float* out = (float*)d_out;

    short* wsS  = (short*)d_ws;
    short* hsb  = wsS;                       // 2,097,152
    short* wqb  = hsb + 2097152;             // 1,048,576
    short* wkb  = wqb + 1048576;
    short* wvb  = wkb + 1048576;
    short* wob  = wvb + 1048576;
    short* qb   = wob + 1048576;             // 2,097,152
    short* kb   = qb  + 2097152;
    short* vtb  = kb  + 2097152;             // [h][d][s]
    short* ctxb = vtb + 2097152;
    short* QaB  = ctxb+ 2097152;             // 6,291,456  [h][s][192]
    short* KaB  = QaB + 6291456;
    short* omtb = KaB + 6291456;             // 131,072    [h][m][d]
    short* OpS  = omtb+ 131072;              // 8,388,608 bf16 [4][16][2048][64]
    float* LpF  = (float*)(OpS + 8388608);   // 131,072 f32 [4][16][2048]

    conv_kernel<<<6272, 256, 0, stream>>>(hs, Wq, Wk, Wv, Wo, omega,
                                          hsb, wqb, wkb, wvb, wob, omtb);
    gemm_mfma<<<dim3(8, 32, 3), 256, 0, stream>>>(hsb, wqb, bq, qb, wkb, bk, kb, wvb, bv, vtb,
                                                  0, 0, 1, S_LEN);
    phi2_kernel<<<dim3(32, 16, 2), 256, 0, stream>>>(qb, kb, omtb, rffb, QaB, KaB);
    flash_mfma<<<dim3(32, 16, KSPL), 128, 0, stream>>>(QaB, KaB, vtb, mask, OpS, LpF);
    merge_kernel<<<2048, 256, 0, stream>>>(OpS, LpF, ctxb);
    gemm_mfma<<<dim3(8, 32, 1), 256, 0, stream>>>(ctxb, wob, bo, out, wob, bo, out, wob, bo, out,
                                                  2, 2, 2, S_LEN);
}